// Round 8
// baseline (360.591 us; speedup 1.0000x reference)
//
#include <hip/hip_runtime.h>

#define N0        200000
#define N1        25000
#define N2        5000
#define FANOUT    16
#define IN_FEATS  500
#define NH        128
#define NC        47
#define K_PAD     512
#define ROWS_A    32          // rows per kA block; LDS tile = 32*512*4B = 64 KB

typedef __attribute__((ext_vector_type(4))) float f32x4;
typedef __attribute__((ext_vector_type(8))) short bf16x8;
typedef __attribute__((ext_vector_type(2))) unsigned int uint2_;
typedef __attribute__((ext_vector_type(4))) unsigned int uint4_;

__device__ __forceinline__ unsigned short f2bf(float f) {
    unsigned int u = __builtin_bit_cast(unsigned int, f);
    u += 0x7fffu + ((u >> 16) & 1u);          // RNE
    return (unsigned short)(u >> 16);
}
__device__ __forceinline__ float bfhi(unsigned int u) {
    return __builtin_bit_cast(float, u & 0xffff0000u);
}
__device__ __forceinline__ float bflo(unsigned int u) {
    return __builtin_bit_cast(float, u << 16);
}
__device__ __forceinline__ void gload_lds16(const void* g, void* l) {
    __builtin_amdgcn_global_load_lds(
        (const __attribute__((address_space(1))) void*)g,
        (__attribute__((address_space(3))) void*)l, 16, 0, 0);
}

// ---------------------------------------------------------------------------
// k0: Wt[c][k] = bf16(W1[k][c]), zero-padded to K_PAD.
// ---------------------------------------------------------------------------
__global__ __launch_bounds__(256) void k0_transpose(
    const float* __restrict__ W1, unsigned short* __restrict__ Wt)
{
    __shared__ unsigned short sm[64][NH];
    const int t = threadIdx.x;
    const int kbase = blockIdx.x * 64;

    for (int r = t >> 7; r < 64; r += 2) {
        const int k = kbase + r;
        const int c = t & (NH - 1);
        sm[r][c] = f2bf(k < IN_FEATS ? W1[(size_t)k * NH + c] : 0.f);
    }
    __syncthreads();

    const int c  = t >> 1;
    const int ko = (t & 1) * 32;
    unsigned short* dst = Wt + (size_t)c * K_PAD + kbase + ko;
    #pragma unroll
    for (int i = 0; i < 32; i += 8) {
        bf16x8 v;
        #pragma unroll
        for (int e = 0; e < 8; ++e) v[e] = (short)sm[ko + i + e][c];
        *(bf16x8*)(dst + i) = v;
    }
}

// ---------------------------------------------------------------------------
// kA v3: dense GEMM H0 = features @ W1 (bf16 MFMA).
// Staging: global_load_lds width-16, f32 tile [32][512B-units swizzled],
// source-address XOR pre-swizzle (unit ^= row&7, clamped in-row -> no OOB).
// Compute: A from LDS (2x ds_read_b128 f32, cvt in-reg), B from global Wt.
// 4 waves: wave w -> rows (w&1)*16..+15, cols (w>>1)*64..+63.
// ---------------------------------------------------------------------------
__global__ __launch_bounds__(256) void kA_gemm(
    const float* __restrict__ features,       // [N0, IN_FEATS]
    const unsigned short* __restrict__ Wt,    // [NH, K_PAD] bf16
    unsigned short* __restrict__ H0)          // [N0, NH] bf16
{
    __shared__ float A[ROWS_A * K_PAD];       // 64 KB; 16B-unit-swizzled rows

    const int tid  = threadIdx.x;
    const int lane = tid & 63;
    const int wv   = tid >> 6;
    const int l15  = lane & 15;
    const int lq   = lane >> 4;               // 0..3
    const int rowbase = blockIdx.x * ROWS_A;

    // ---- Phase A: async staging. wave wv stages rows wv*8 .. wv*8+7 ----
    // phys 16B-unit p of row r  <-  logical unit (p ^ (r&7)), clamped to 124
    // (row = 2000 B = 125 units; units 125..127 hold junk, masked at kk=15).
    #pragma unroll
    for (int i = 0; i < 16; ++i) {
        const int r = wv * 8 + (i >> 1);
        const int h = i & 1;
        const int p = h * 64 + lane;
        int lu = p ^ (r & 7);
        lu = lu > 124 ? 124 : lu;
        const char* src = (const char*)(features + (size_t)(rowbase + r) * IN_FEATS) + lu * 16;
        char* dst = (char*)A + r * 2048 + h * 1024;   // wave-uniform base
        gload_lds16(src, dst);
    }
    __syncthreads();

    // ---- Phase B: MFMA. wave -> 16 rows x 64 cols ----
    const int rt = wv & 1;
    const int ch = wv >> 1;

    f32x4 acc[4];
    #pragma unroll
    for (int n = 0; n < 4; ++n) acc[n] = (f32x4){0.f,0.f,0.f,0.f};

    const int arow = rt * 16 + l15;
    const char* arow_p = (const char*)A + arow * 2048;
    const int sw = arow & 7;

    #pragma unroll 4
    for (int kk = 0; kk < 16; ++kk) {
        const int ke = kk * 32 + lq * 8;      // element offset
        const int u  = kk * 8 + lq * 2;       // logical 16B-unit (even)
        f32x4 x0 = *(const f32x4*)(arow_p + ((u     ^ sw) * 16));
        f32x4 x1 = *(const f32x4*)(arow_p + (((u+1) ^ sw) * 16));
        if (kk == 15) {                        // K tail mask (elems >= 500)
            if (ke >= IN_FEATS)     x0 = (f32x4){0.f,0.f,0.f,0.f};
            if (ke + 4 >= IN_FEATS) x1 = (f32x4){0.f,0.f,0.f,0.f};
        }
        bf16x8 a;
        a[0]=(short)f2bf(x0.x); a[1]=(short)f2bf(x0.y); a[2]=(short)f2bf(x0.z); a[3]=(short)f2bf(x0.w);
        a[4]=(short)f2bf(x1.x); a[5]=(short)f2bf(x1.y); a[6]=(short)f2bf(x1.z); a[7]=(short)f2bf(x1.w);
        #pragma unroll
        for (int nt = 0; nt < 4; ++nt) {
            const int col = ch * 64 + nt * 16 + l15;
            bf16x8 b = *(const bf16x8*)(Wt + (size_t)col * K_PAD + ke);
            acc[nt] = __builtin_amdgcn_mfma_f32_16x16x32_bf16(a, b, acc[nt], 0, 0, 0);
        }
    }

    // ---- Epilogue: H0 bf16 ----
    #pragma unroll
    for (int nt = 0; nt < 4; ++nt) {
        const int col = ch * 64 + nt * 16 + l15;
        #pragma unroll
        for (int rr = 0; rr < 4; ++rr) {
            const int row = rowbase + rt * 16 + lq * 4 + rr;
            H0[(size_t)row * NH + col] = f2bf(acc[nt][rr]);
        }
    }
}

// ---------------------------------------------------------------------------
// kB v2: h1cat[i] = [m + b1, relu(m + b1)], m = mean_j H0[src0[i,j]].
// 4 rows per wave: lane-group g (16 lanes) owns row, lane covers 8 cols
// (16 B/lane, all 64 lanes active per gather instr).
// ---------------------------------------------------------------------------
__global__ __launch_bounds__(256) void kB_gather(
    const unsigned short* __restrict__ H0,    // [N0, NH] bf16
    const int*   __restrict__ src0,           // [N1, FANOUT]
    const float* __restrict__ b1,             // [NH]
    unsigned short* __restrict__ h1cat)       // [N1, 2*NH] bf16
{
    const int lane = threadIdx.x & 63;
    const int wv   = threadIdx.x >> 6;
    const int g    = lane >> 4;               // row-group 0..3
    const int l15  = lane & 15;
    const int row  = blockIdx.x * 16 + wv * 4 + g;
    if (row >= N1) return;

    const int rb = row * FANOUT;
    const int c8 = l15 * 8;                   // 8 cols per lane

    float acc[8] = {0.f,0.f,0.f,0.f,0.f,0.f,0.f,0.f};
    #pragma unroll 4
    for (int j = 0; j < FANOUT; ++j) {
        const int nb = src0[rb + j];
        uint4_ v = *(const uint4_*)(H0 + (size_t)nb * NH + c8);
        acc[0] += bflo(v.x); acc[1] += bfhi(v.x);
        acc[2] += bflo(v.y); acc[3] += bfhi(v.y);
        acc[4] += bflo(v.z); acc[5] += bfhi(v.z);
        acc[6] += bflo(v.w); acc[7] += bfhi(v.w);
    }

    f32x4 b_lo = *(const f32x4*)(b1 + c8);
    f32x4 b_hi = *(const f32x4*)(b1 + c8 + 4);
    float h[8];
    h[0] = acc[0]*0.0625f + b_lo.x; h[1] = acc[1]*0.0625f + b_lo.y;
    h[2] = acc[2]*0.0625f + b_lo.z; h[3] = acc[3]*0.0625f + b_lo.w;
    h[4] = acc[4]*0.0625f + b_hi.x; h[5] = acc[5]*0.0625f + b_hi.y;
    h[6] = acc[6]*0.0625f + b_hi.z; h[7] = acc[7]*0.0625f + b_hi.w;

    uint4_ wh, wr;
    wh.x = (unsigned int)f2bf(h[0]) | ((unsigned int)f2bf(h[1]) << 16);
    wh.y = (unsigned int)f2bf(h[2]) | ((unsigned int)f2bf(h[3]) << 16);
    wh.z = (unsigned int)f2bf(h[4]) | ((unsigned int)f2bf(h[5]) << 16);
    wh.w = (unsigned int)f2bf(h[6]) | ((unsigned int)f2bf(h[7]) << 16);
    wr.x = (unsigned int)f2bf(h[0]>0.f?h[0]:0.f) | ((unsigned int)f2bf(h[1]>0.f?h[1]:0.f) << 16);
    wr.y = (unsigned int)f2bf(h[2]>0.f?h[2]:0.f) | ((unsigned int)f2bf(h[3]>0.f?h[3]:0.f) << 16);
    wr.z = (unsigned int)f2bf(h[4]>0.f?h[4]:0.f) | ((unsigned int)f2bf(h[5]>0.f?h[5]:0.f) << 16);
    wr.w = (unsigned int)f2bf(h[6]>0.f?h[6]:0.f) | ((unsigned int)f2bf(h[7]>0.f?h[7]:0.f) << 16);

    unsigned short* dst = h1cat + (size_t)row * 256;
    *(uint4_*)(dst + c8)       = wh;
    *(uint4_*)(dst + NH + c8)  = wr;
}

// ---------------------------------------------------------------------------
// k2: gather-mean over bf16 h1cat + f32 GEMM [8x256]@[256x47] + bias.
// ---------------------------------------------------------------------------
__global__ __launch_bounds__(256) void k2_fused(
    const unsigned short* __restrict__ h1cat, // [N1, 256] bf16
    const int*   __restrict__ src1,           // [N2, FANOUT]
    const float* __restrict__ W2,             // [256, NC]
    const float* __restrict__ b2,             // [NC]
    float*       __restrict__ out)            // [N2, NC]
{
    __shared__ float sm[8][256];

    const int tid = threadIdx.x;
    const int r   = tid >> 5;
    const int s   = tid & 31;
    const int row = blockIdx.x * 8 + r;

    float acc[8] = {0.f,0.f,0.f,0.f,0.f,0.f,0.f,0.f};
    #pragma unroll
    for (int j = 0; j < FANOUT; ++j) {
        const int nb = src1[row * FANOUT + j];
        uint4_ v = *(const uint4_*)(h1cat + (size_t)nb * 256 + s * 8);
        acc[0] += bflo(v.x); acc[1] += bfhi(v.x);
        acc[2] += bflo(v.y); acc[3] += bfhi(v.y);
        acc[4] += bflo(v.z); acc[5] += bfhi(v.z);
        acc[6] += bflo(v.w); acc[7] += bfhi(v.w);
    }
    #pragma unroll
    for (int e = 0; e < 8; ++e) sm[r][s * 8 + e] = acc[e] * 0.0625f;
    __syncthreads();

    const int c0 = s, c1 = s + 32;
    float o0 = b2[c0];
    float o1 = (c1 < NC) ? b2[c1] : 0.f;
    for (int k = 0; k < 256; k += 4) {
        f32x4 mv = *(const f32x4*)&sm[r][k];
        #pragma unroll
        for (int e = 0; e < 4; ++e) {
            const float* wrow = W2 + (size_t)(k + e) * NC;
            o0 += mv[e] * wrow[c0];
            if (c1 < NC) o1 += mv[e] * wrow[c1];
        }
    }
    out[(size_t)row * NC + c0] = o0;
    if (c1 < NC) out[(size_t)row * NC + c1] = o1;
}

extern "C" void kernel_launch(void* const* d_in, const int* in_sizes, int n_in,
                              void* d_out, int out_size, void* d_ws, size_t ws_size,
                              hipStream_t stream)
{
    const float* features = (const float*)d_in[0];
    const int*   src0     = (const int*)  d_in[1];
    const int*   src1     = (const int*)  d_in[2];
    const float* W1       = (const float*)d_in[3];
    const float* b1       = (const float*)d_in[4];
    const float* W2       = (const float*)d_in[5];
    const float* b2       = (const float*)d_in[6];
    float*       out      = (float*)d_out;

    unsigned short* Wt    = (unsigned short*)d_ws;        // [NH][K_PAD]  = 128 KB
    unsigned short* H0    = Wt + (size_t)NH * K_PAD;      // [N0][NH] bf16 = 51.2 MB
    unsigned short* h1cat = H0 + (size_t)N0 * NH;         // [N1][256] bf16 = 12.8 MB

    hipLaunchKernelGGL(k0_transpose, dim3(K_PAD / 64), dim3(256), 0, stream, W1, Wt);
    hipLaunchKernelGGL(kA_gemm,   dim3(N0 / ROWS_A),      dim3(256), 0, stream, features, Wt, H0);
    hipLaunchKernelGGL(kB_gather, dim3((N1 + 15) / 16),   dim3(256), 0, stream, H0, src0, b1, h1cat);
    hipLaunchKernelGGL(k2_fused,  dim3(N2 / 8),           dim3(256), 0, stream, h1cat, src1, W2, b2, out);
}

// Round 9
// 312.586 us; speedup vs baseline: 1.1536x; 1.1536x over previous
//
#include <hip/hip_runtime.h>

#define N0        200000
#define N1        25000
#define N2        5000
#define FANOUT    16
#define IN_FEATS  500
#define NH        128
#define NC        47
#define K_PAD     512
#define TILE_R    16                    // rows per kA tile
#define NTILES    (N0 / TILE_R)         // 12500
#define GRID_A    1024                  // persistent-ish kA grid (4 blocks/CU)

typedef __attribute__((ext_vector_type(4))) float f32x4;
typedef __attribute__((ext_vector_type(8))) short bf16x8;
typedef __attribute__((ext_vector_type(2))) unsigned int uint2_;
typedef __attribute__((ext_vector_type(4))) unsigned int uint4_;

__device__ __forceinline__ unsigned short f2bf(float f) {
    unsigned int u = __builtin_bit_cast(unsigned int, f);
    u += 0x7fffu + ((u >> 16) & 1u);          // RNE
    return (unsigned short)(u >> 16);
}
__device__ __forceinline__ float bfhi(unsigned int u) {
    return __builtin_bit_cast(float, u & 0xffff0000u);
}
__device__ __forceinline__ float bflo(unsigned int u) {
    return __builtin_bit_cast(float, u << 16);
}

// ---------------------------------------------------------------------------
// k0: Wt[c][k] = bf16(W1[k][c]), zero-padded to K_PAD.
// ---------------------------------------------------------------------------
__global__ __launch_bounds__(256) void k0_transpose(
    const float* __restrict__ W1, unsigned short* __restrict__ Wt)
{
    __shared__ unsigned short sm[64][NH];
    const int t = threadIdx.x;
    const int kbase = blockIdx.x * 64;

    for (int r = t >> 7; r < 64; r += 2) {
        const int k = kbase + r;
        const int c = t & (NH - 1);
        sm[r][c] = f2bf(k < IN_FEATS ? W1[(size_t)k * NH + c] : 0.f);
    }
    __syncthreads();

    const int c  = t >> 1;
    const int ko = (t & 1) * 32;
    unsigned short* dst = Wt + (size_t)c * K_PAD + kbase + ko;
    #pragma unroll
    for (int i = 0; i < 32; i += 8) {
        bf16x8 v;
        #pragma unroll
        for (int e = 0; e < 8; ++e) v[e] = (short)sm[ko + i + e][c];
        *(bf16x8*)(dst + i) = v;
    }
}

// ---------------------------------------------------------------------------
// kA v5: dense GEMM H0 = features @ W1 (bf16 MFMA), persistent 2-phase
// pipeline. Per 16-row tile: issue next tile's coalesced f32x4 loads ->
// compute current tile (LDS bf16 A, XOR-swizzled; B from L2-resident Wt)
// -> cvt+ds_write next buffer (vmcnt lands here, hidden under MFMA) ->
// one barrier -> swap. K-pad [500,512) pre-zeroed once (no tail masking;
// Wt pad is also zero).
// ---------------------------------------------------------------------------
__global__ __launch_bounds__(256, 4) void kA_gemm(
    const float* __restrict__ features,       // [N0, IN_FEATS]
    const unsigned short* __restrict__ Wt,    // [NH, K_PAD] bf16
    unsigned short* __restrict__ H0)          // [N0, NH] bf16
{
    __shared__ unsigned short A[2][TILE_R * K_PAD];   // 2 x 16 KB, swizzled rows

    const int tid  = threadIdx.x;
    const int lane = tid & 63;
    const int wv   = tid >> 6;                // 0..3 (col group)
    const int l15  = lane & 15;
    const int lq   = lane >> 4;               // 0..3

    // zero the K-pad region (k in [500,512)) of both buffers, once
    if (tid < 96) {
        const int b  = tid / 48, rem = tid % 48;
        const int r  = rem / 3,  j   = rem % 3;
        const int k4 = 500 + j * 4;
        uint2_ z = {0u, 0u};
        *(uint2_*)((char*)&A[b][0] + r * 1024 + ((k4 * 2) ^ ((r & 7) << 4))) = z;
    }

    f32x4 ld[8];
    int cur = 0;
    int t = blockIdx.x;

    // ---- prologue: stage tile t into buffer 0 ----
    {
        const f32x4* slab = (const f32x4*)(features + (size_t)t * TILE_R * IN_FEATS);
        #pragma unroll
        for (int i = 0; i < 7; ++i) ld[i] = __builtin_nontemporal_load(slab + tid + 256 * i);
        if (tid < 208) ld[7] = __builtin_nontemporal_load(slab + tid + 1792);
        #pragma unroll
        for (int i = 0; i < 8; ++i) {
            if (i < 7 || tid < 208) {
                const int c  = tid + 256 * i;          // chunk in [0,2000)
                const int r  = c / 125;                // row 0..15
                const int k4 = (c - r * 125) * 4;      // elem 0..496
                uint2_ w;
                w.x = (unsigned int)f2bf(ld[i].x) | ((unsigned int)f2bf(ld[i].y) << 16);
                w.y = (unsigned int)f2bf(ld[i].z) | ((unsigned int)f2bf(ld[i].w) << 16);
                *(uint2_*)((char*)&A[0][0] + r * 1024 + ((k4 * 2) ^ ((r & 7) << 4))) = w;
            }
        }
    }
    __syncthreads();

    // ---- main pipelined loop ----
    while (t < NTILES) {
        const int tn = t + GRID_A;

        // (1) issue next tile's loads (coalesced, nontemporal)
        if (tn < NTILES) {
            const f32x4* slab = (const f32x4*)(features + (size_t)tn * TILE_R * IN_FEATS);
            #pragma unroll
            for (int i = 0; i < 7; ++i) ld[i] = __builtin_nontemporal_load(slab + tid + 256 * i);
            if (tid < 208) ld[7] = __builtin_nontemporal_load(slab + tid + 1792);
        }

        // (2) compute current tile: wave wv -> 16 rows x cols [wv*32, wv*32+32)
        f32x4 acc[2];
        acc[0] = (f32x4){0.f,0.f,0.f,0.f};
        acc[1] = (f32x4){0.f,0.f,0.f,0.f};
        const char* base = (const char*)&A[cur][0];
        const int abase = l15 * 1024;
        const int sw    = (l15 & 7) << 4;

        #pragma unroll 4
        for (int kk = 0; kk < 16; ++kk) {
            const int ke = kk * 32 + lq * 8;
            bf16x8 a = *(const bf16x8*)(base + abase + ((ke * 2) ^ sw));
            #pragma unroll
            for (int nt = 0; nt < 2; ++nt) {
                const int col = wv * 32 + nt * 16 + l15;
                bf16x8 b = *(const bf16x8*)(Wt + (size_t)col * K_PAD + ke);
                acc[nt] = __builtin_amdgcn_mfma_f32_16x16x32_bf16(a, b, acc[nt], 0, 0, 0);
            }
        }

        // epilogue: H0 bf16
        const int rowb = t * TILE_R;
        #pragma unroll
        for (int nt = 0; nt < 2; ++nt) {
            const int col = wv * 32 + nt * 16 + l15;
            #pragma unroll
            for (int rr = 0; rr < 4; ++rr) {
                H0[(size_t)(rowb + lq * 4 + rr) * NH + col] = f2bf(acc[nt][rr]);
            }
        }

        // (3) write next tile into the other buffer (vmcnt waits land here)
        if (tn < NTILES) {
            char* nb = (char*)&A[cur ^ 1][0];
            #pragma unroll
            for (int i = 0; i < 8; ++i) {
                if (i < 7 || tid < 208) {
                    const int c  = tid + 256 * i;
                    const int r  = c / 125;
                    const int k4 = (c - r * 125) * 4;
                    uint2_ w;
                    w.x = (unsigned int)f2bf(ld[i].x) | ((unsigned int)f2bf(ld[i].y) << 16);
                    w.y = (unsigned int)f2bf(ld[i].z) | ((unsigned int)f2bf(ld[i].w) << 16);
                    *(uint2_*)(nb + r * 1024 + ((k4 * 2) ^ ((r & 7) << 4))) = w;
                }
            }
        }

        // (4) one barrier per tile
        __syncthreads();
        cur ^= 1;
        t = tn;
    }
}

// ---------------------------------------------------------------------------
// kB: h1cat[i] = [m + b1, relu(m + b1)], m = mean_j H0[src0[i,j]].
// 4 rows per wave: 16-lane group owns a row, lane covers 8 cols (16 B/lane).
// ---------------------------------------------------------------------------
__global__ __launch_bounds__(256) void kB_gather(
    const unsigned short* __restrict__ H0,    // [N0, NH] bf16
    const int*   __restrict__ src0,           // [N1, FANOUT]
    const float* __restrict__ b1,             // [NH]
    unsigned short* __restrict__ h1cat)       // [N1, 2*NH] bf16
{
    const int lane = threadIdx.x & 63;
    const int wv   = threadIdx.x >> 6;
    const int g    = lane >> 4;
    const int l15  = lane & 15;
    const int row  = blockIdx.x * 16 + wv * 4 + g;
    if (row >= N1) return;

    const int rb = row * FANOUT;
    const int c8 = l15 * 8;

    float acc[8] = {0.f,0.f,0.f,0.f,0.f,0.f,0.f,0.f};
    #pragma unroll 4
    for (int j = 0; j < FANOUT; ++j) {
        const int nb = src0[rb + j];
        uint4_ v = *(const uint4_*)(H0 + (size_t)nb * NH + c8);
        acc[0] += bflo(v.x); acc[1] += bfhi(v.x);
        acc[2] += bflo(v.y); acc[3] += bfhi(v.y);
        acc[4] += bflo(v.z); acc[5] += bfhi(v.z);
        acc[6] += bflo(v.w); acc[7] += bfhi(v.w);
    }

    f32x4 b_lo = *(const f32x4*)(b1 + c8);
    f32x4 b_hi = *(const f32x4*)(b1 + c8 + 4);
    float h[8];
    h[0] = acc[0]*0.0625f + b_lo.x; h[1] = acc[1]*0.0625f + b_lo.y;
    h[2] = acc[2]*0.0625f + b_lo.z; h[3] = acc[3]*0.0625f + b_lo.w;
    h[4] = acc[4]*0.0625f + b_hi.x; h[5] = acc[5]*0.0625f + b_hi.y;
    h[6] = acc[6]*0.0625f + b_hi.z; h[7] = acc[7]*0.0625f + b_hi.w;

    uint4_ wh, wr;
    wh.x = (unsigned int)f2bf(h[0]) | ((unsigned int)f2bf(h[1]) << 16);
    wh.y = (unsigned int)f2bf(h[2]) | ((unsigned int)f2bf(h[3]) << 16);
    wh.z = (unsigned int)f2bf(h[4]) | ((unsigned int)f2bf(h[5]) << 16);
    wh.w = (unsigned int)f2bf(h[6]) | ((unsigned int)f2bf(h[7]) << 16);
    wr.x = (unsigned int)f2bf(h[0]>0.f?h[0]:0.f) | ((unsigned int)f2bf(h[1]>0.f?h[1]:0.f) << 16);
    wr.y = (unsigned int)f2bf(h[2]>0.f?h[2]:0.f) | ((unsigned int)f2bf(h[3]>0.f?h[3]:0.f) << 16);
    wr.z = (unsigned int)f2bf(h[4]>0.f?h[4]:0.f) | ((unsigned int)f2bf(h[5]>0.f?h[5]:0.f) << 16);
    wr.w = (unsigned int)f2bf(h[6]>0.f?h[6]:0.f) | ((unsigned int)f2bf(h[7]>0.f?h[7]:0.f) << 16);

    unsigned short* dst = h1cat + (size_t)row * 256;
    *(uint4_*)(dst + c8)       = wh;
    *(uint4_*)(dst + NH + c8)  = wr;
}

// ---------------------------------------------------------------------------
// k2: gather-mean over bf16 h1cat + f32 GEMM [8x256]@[256x47] + bias.
// ---------------------------------------------------------------------------
__global__ __launch_bounds__(256) void k2_fused(
    const unsigned short* __restrict__ h1cat, // [N1, 256] bf16
    const int*   __restrict__ src1,           // [N2, FANOUT]
    const float* __restrict__ W2,             // [256, NC]
    const float* __restrict__ b2,             // [NC]
    float*       __restrict__ out)            // [N2, NC]
{
    __shared__ float sm[8][256];

    const int tid = threadIdx.x;
    const int r   = tid >> 5;
    const int s   = tid & 31;
    const int row = blockIdx.x * 8 + r;

    float acc[8] = {0.f,0.f,0.f,0.f,0.f,0.f,0.f,0.f};
    #pragma unroll
    for (int j = 0; j < FANOUT; ++j) {
        const int nb = src1[row * FANOUT + j];
        uint4_ v = *(const uint4_*)(h1cat + (size_t)nb * 256 + s * 8);
        acc[0] += bflo(v.x); acc[1] += bfhi(v.x);
        acc[2] += bflo(v.y); acc[3] += bfhi(v.y);
        acc[4] += bflo(v.z); acc[5] += bfhi(v.z);
        acc[6] += bflo(v.w); acc[7] += bfhi(v.w);
    }
    #pragma unroll
    for (int e = 0; e < 8; ++e) sm[r][s * 8 + e] = acc[e] * 0.0625f;
    __syncthreads();

    const int c0 = s, c1 = s + 32;
    float o0 = b2[c0];
    float o1 = (c1 < NC) ? b2[c1] : 0.f;
    for (int k = 0; k < 256; k += 4) {
        f32x4 mv = *(const f32x4*)&sm[r][k];
        #pragma unroll
        for (int e = 0; e < 4; ++e) {
            const float* wrow = W2 + (size_t)(k + e) * NC;
            o0 += mv[e] * wrow[c0];
            if (c1 < NC) o1 += mv[e] * wrow[c1];
        }
    }
    out[(size_t)row * NC + c0] = o0;
    if (c1 < NC) out[(size_t)row * NC + c1] = o1;
}

extern "C" void kernel_launch(void* const* d_in, const int* in_sizes, int n_in,
                              void* d_out, int out_size, void* d_ws, size_t ws_size,
                              hipStream_t stream)
{
    const float* features = (const float*)d_in[0];
    const int*   src0     = (const int*)  d_in[1];
    const int*   src1     = (const int*)  d_in[2];
    const float* W1       = (const float*)d_in[3];
    const float* b1       = (const float*)d_in[4];
    const float* W2       = (const float*)d_in[5];
    const float* b2       = (const float*)d_in[6];
    float*       out      = (float*)d_out;

    unsigned short* Wt    = (unsigned short*)d_ws;        // [NH][K_PAD]  = 128 KB
    unsigned short* H0    = Wt + (size_t)NH * K_PAD;      // [N0][NH] bf16 = 51.2 MB
    unsigned short* h1cat = H0 + (size_t)N0 * NH;         // [N1][256] bf16 = 12.8 MB

    hipLaunchKernelGGL(k0_transpose, dim3(K_PAD / 64), dim3(256), 0, stream, W1, Wt);
    hipLaunchKernelGGL(kA_gemm,   dim3(GRID_A),          dim3(256), 0, stream, features, Wt, H0);
    hipLaunchKernelGGL(kB_gather, dim3((N1 + 15) / 16),  dim3(256), 0, stream, H0, src0, b1, h1cat);
    hipLaunchKernelGGL(k2_fused,  dim3(N2 / 8),          dim3(256), 0, stream, h1cat, src1, W2, b2, out);
}

// Round 10
// 181.223 us; speedup vs baseline: 1.9898x; 1.7249x over previous
//
#include <hip/hip_runtime.h>

#define N0        200000
#define N1        25000
#define N2        5000
#define FANOUT    16
#define IN_FEATS  500
#define NH        128
#define NC        47
#define K_PAD     512
#define TILE_R    16                    // rows per kA tile
#define NTILES    (N0 / TILE_R)         // 12500
#define GRID_A    512                   // 2 blocks/CU (8 waves each)

typedef __attribute__((ext_vector_type(4))) float f32x4;
typedef __attribute__((ext_vector_type(8))) short bf16x8;
typedef __attribute__((ext_vector_type(2))) unsigned int uint2_;
typedef __attribute__((ext_vector_type(4))) unsigned int uint4_;

__device__ __forceinline__ unsigned short f2bf(float f) {
    unsigned int u = __builtin_bit_cast(unsigned int, f);
    u += 0x7fffu + ((u >> 16) & 1u);          // RNE
    return (unsigned short)(u >> 16);
}
__device__ __forceinline__ float bfhi(unsigned int u) {
    return __builtin_bit_cast(float, u & 0xffff0000u);
}
__device__ __forceinline__ float bflo(unsigned int u) {
    return __builtin_bit_cast(float, u << 16);
}

// ---------------------------------------------------------------------------
// k0: Wt[c][k] = bf16(W1[k][c]), zero-padded to K_PAD.
// ---------------------------------------------------------------------------
__global__ __launch_bounds__(256) void k0_transpose(
    const float* __restrict__ W1, unsigned short* __restrict__ Wt)
{
    __shared__ unsigned short sm[64][NH];
    const int t = threadIdx.x;
    const int kbase = blockIdx.x * 64;

    for (int r = t >> 7; r < 64; r += 2) {
        const int k = kbase + r;
        const int c = t & (NH - 1);
        sm[r][c] = f2bf(k < IN_FEATS ? W1[(size_t)k * NH + c] : 0.f);
    }
    __syncthreads();

    const int c  = t >> 1;
    const int ko = (t & 1) * 32;
    unsigned short* dst = Wt + (size_t)c * K_PAD + kbase + ko;
    #pragma unroll
    for (int i = 0; i < 32; i += 8) {
        bf16x8 v;
        #pragma unroll
        for (int e = 0; e < 8; ++e) v[e] = (short)sm[ko + i + e][c];
        *(bf16x8*)(dst + i) = v;
    }
}

// ---------------------------------------------------------------------------
// kA v6: dense GEMM H0 = features @ W1 (bf16 MFMA), B held in REGISTERS.
// 512 thr / 8 waves; wave wv owns cols [wv*16, wv*16+16) and preloads its
// 16 B-fragments once (64 VGPRs, static-indexed). Main loop: double-buffered
// 16-row A-tile (XOR-swizzled bf16 LDS); per kk-step 1 ds_read + 1 MFMA,
// ZERO global loads. Pipeline: issue next loads -> compute -> write next
// buffer -> barrier.
// ---------------------------------------------------------------------------
__global__ __launch_bounds__(512, 4) void kA_gemm(
    const float* __restrict__ features,       // [N0, IN_FEATS]
    const unsigned short* __restrict__ Wt,    // [NH, K_PAD] bf16
    unsigned short* __restrict__ H0)          // [N0, NH] bf16
{
    __shared__ unsigned short A[2][TILE_R * K_PAD];   // 2 x 16 KB, swizzled rows

    const int tid  = threadIdx.x;
    const int lane = tid & 63;
    const int wv   = tid >> 6;                // 0..7 (16-col group)
    const int l15  = lane & 15;
    const int lq   = lane >> 4;               // 0..3

    // ---- preload this wave's B-fragments (cols wv*16+l15, one-time) ----
    bf16x8 bfrag[16];
    {
        const unsigned short* bp = Wt + (size_t)(wv * 16 + l15) * K_PAD + lq * 8;
        #pragma unroll
        for (int kk = 0; kk < 16; ++kk)
            bfrag[kk] = *(const bf16x8*)(bp + kk * 32);
    }

    // zero the K-pad region (k in [500,512)) of both buffers, once
    if (tid < 96) {
        const int b  = tid / 48, rem = tid % 48;
        const int r  = rem / 3,  j   = rem % 3;
        const int k4 = 500 + j * 4;
        uint2_ z = {0u, 0u};
        *(uint2_*)((char*)&A[b][0] + r * 1024 + ((k4 * 2) ^ ((r & 7) << 4))) = z;
    }

    f32x4 ld[4];
    int cur = 0;
    int t = blockIdx.x;

    // ---- prologue: stage tile t into buffer 0 ----
    {
        const f32x4* slab = (const f32x4*)(features + (size_t)t * TILE_R * IN_FEATS);
        #pragma unroll
        for (int i = 0; i < 3; ++i) ld[i] = __builtin_nontemporal_load(slab + tid + 512 * i);
        if (tid < 464) ld[3] = __builtin_nontemporal_load(slab + tid + 1536);
        #pragma unroll
        for (int i = 0; i < 4; ++i) {
            if (i < 3 || tid < 464) {
                const int c  = tid + 512 * i;          // chunk in [0,2000)
                const int r  = c / 125;                // row 0..15
                const int k4 = (c - r * 125) * 4;      // elem 0..496
                uint2_ w;
                w.x = (unsigned int)f2bf(ld[i].x) | ((unsigned int)f2bf(ld[i].y) << 16);
                w.y = (unsigned int)f2bf(ld[i].z) | ((unsigned int)f2bf(ld[i].w) << 16);
                *(uint2_*)((char*)&A[0][0] + r * 1024 + ((k4 * 2) ^ ((r & 7) << 4))) = w;
            }
        }
    }
    __syncthreads();

    // ---- main pipelined loop ----
    while (t < NTILES) {
        const int tn = t + GRID_A;

        // (1) issue next tile's loads (coalesced, nontemporal)
        if (tn < NTILES) {
            const f32x4* slab = (const f32x4*)(features + (size_t)tn * TILE_R * IN_FEATS);
            #pragma unroll
            for (int i = 0; i < 3; ++i) ld[i] = __builtin_nontemporal_load(slab + tid + 512 * i);
            if (tid < 464) ld[3] = __builtin_nontemporal_load(slab + tid + 1536);
        }

        // (2) compute current tile: wave wv -> 16 rows x 16 cols, B in regs
        f32x4 acc = (f32x4){0.f, 0.f, 0.f, 0.f};
        const char* base = (const char*)&A[cur][0];
        const int abase = l15 * 1024;
        const int sw    = (l15 & 7) << 4;

        #pragma unroll
        for (int kk = 0; kk < 16; ++kk) {
            const int ke = kk * 32 + lq * 8;
            bf16x8 a = *(const bf16x8*)(base + abase + ((ke * 2) ^ sw));
            acc = __builtin_amdgcn_mfma_f32_16x16x32_bf16(a, bfrag[kk], acc, 0, 0, 0);
        }

        // epilogue: H0 bf16 (col = wv*16+l15, rows lq*4+rr)
        const int rowb = t * TILE_R;
        const int col  = wv * 16 + l15;
        #pragma unroll
        for (int rr = 0; rr < 4; ++rr) {
            H0[(size_t)(rowb + lq * 4 + rr) * NH + col] = f2bf(acc[rr]);
        }

        // (3) write next tile into the other buffer (vmcnt waits land here)
        if (tn < NTILES) {
            char* nb = (char*)&A[cur ^ 1][0];
            #pragma unroll
            for (int i = 0; i < 4; ++i) {
                if (i < 3 || tid < 464) {
                    const int c  = tid + 512 * i;
                    const int r  = c / 125;
                    const int k4 = (c - r * 125) * 4;
                    uint2_ w;
                    w.x = (unsigned int)f2bf(ld[i].x) | ((unsigned int)f2bf(ld[i].y) << 16);
                    w.y = (unsigned int)f2bf(ld[i].z) | ((unsigned int)f2bf(ld[i].w) << 16);
                    *(uint2_*)(nb + r * 1024 + ((k4 * 2) ^ ((r & 7) << 4))) = w;
                }
            }
        }

        // (4) one barrier per tile
        __syncthreads();
        cur ^= 1;
        t = tn;
    }
}

// ---------------------------------------------------------------------------
// kB: h1cat[i] = [m + b1, relu(m + b1)], m = mean_j H0[src0[i,j]].
// 4 rows per wave: 16-lane group owns a row, lane covers 8 cols (16 B/lane).
// ---------------------------------------------------------------------------
__global__ __launch_bounds__(256) void kB_gather(
    const unsigned short* __restrict__ H0,    // [N0, NH] bf16
    const int*   __restrict__ src0,           // [N1, FANOUT]
    const float* __restrict__ b1,             // [NH]
    unsigned short* __restrict__ h1cat)       // [N1, 2*NH] bf16
{
    const int lane = threadIdx.x & 63;
    const int wv   = threadIdx.x >> 6;
    const int g    = lane >> 4;
    const int l15  = lane & 15;
    const int row  = blockIdx.x * 16 + wv * 4 + g;
    if (row >= N1) return;

    const int rb = row * FANOUT;
    const int c8 = l15 * 8;

    float acc[8] = {0.f,0.f,0.f,0.f,0.f,0.f,0.f,0.f};
    #pragma unroll 4
    for (int j = 0; j < FANOUT; ++j) {
        const int nb = src0[rb + j];
        uint4_ v = *(const uint4_*)(H0 + (size_t)nb * NH + c8);
        acc[0] += bflo(v.x); acc[1] += bfhi(v.x);
        acc[2] += bflo(v.y); acc[3] += bfhi(v.y);
        acc[4] += bflo(v.z); acc[5] += bfhi(v.z);
        acc[6] += bflo(v.w); acc[7] += bfhi(v.w);
    }

    f32x4 b_lo = *(const f32x4*)(b1 + c8);
    f32x4 b_hi = *(const f32x4*)(b1 + c8 + 4);
    float h[8];
    h[0] = acc[0]*0.0625f + b_lo.x; h[1] = acc[1]*0.0625f + b_lo.y;
    h[2] = acc[2]*0.0625f + b_lo.z; h[3] = acc[3]*0.0625f + b_lo.w;
    h[4] = acc[4]*0.0625f + b_hi.x; h[5] = acc[5]*0.0625f + b_hi.y;
    h[6] = acc[6]*0.0625f + b_hi.z; h[7] = acc[7]*0.0625f + b_hi.w;

    uint4_ wh, wr;
    wh.x = (unsigned int)f2bf(h[0]) | ((unsigned int)f2bf(h[1]) << 16);
    wh.y = (unsigned int)f2bf(h[2]) | ((unsigned int)f2bf(h[3]) << 16);
    wh.z = (unsigned int)f2bf(h[4]) | ((unsigned int)f2bf(h[5]) << 16);
    wh.w = (unsigned int)f2bf(h[6]) | ((unsigned int)f2bf(h[7]) << 16);
    wr.x = (unsigned int)f2bf(h[0]>0.f?h[0]:0.f) | ((unsigned int)f2bf(h[1]>0.f?h[1]:0.f) << 16);
    wr.y = (unsigned int)f2bf(h[2]>0.f?h[2]:0.f) | ((unsigned int)f2bf(h[3]>0.f?h[3]:0.f) << 16);
    wr.z = (unsigned int)f2bf(h[4]>0.f?h[4]:0.f) | ((unsigned int)f2bf(h[5]>0.f?h[5]:0.f) << 16);
    wr.w = (unsigned int)f2bf(h[6]>0.f?h[6]:0.f) | ((unsigned int)f2bf(h[7]>0.f?h[7]:0.f) << 16);

    unsigned short* dst = h1cat + (size_t)row * 256;
    *(uint4_*)(dst + c8)       = wh;
    *(uint4_*)(dst + NH + c8)  = wr;
}

// ---------------------------------------------------------------------------
// k2: gather-mean over bf16 h1cat + f32 GEMM [8x256]@[256x47] + bias.
// ---------------------------------------------------------------------------
__global__ __launch_bounds__(256) void k2_fused(
    const unsigned short* __restrict__ h1cat, // [N1, 256] bf16
    const int*   __restrict__ src1,           // [N2, FANOUT]
    const float* __restrict__ W2,             // [256, NC]
    const float* __restrict__ b2,             // [NC]
    float*       __restrict__ out)            // [N2, NC]
{
    __shared__ float sm[8][256];

    const int tid = threadIdx.x;
    const int r   = tid >> 5;
    const int s   = tid & 31;
    const int row = blockIdx.x * 8 + r;

    float acc[8] = {0.f,0.f,0.f,0.f,0.f,0.f,0.f,0.f};
    #pragma unroll
    for (int j = 0; j < FANOUT; ++j) {
        const int nb = src1[row * FANOUT + j];
        uint4_ v = *(const uint4_*)(h1cat + (size_t)nb * 256 + s * 8);
        acc[0] += bflo(v.x); acc[1] += bfhi(v.x);
        acc[2] += bflo(v.y); acc[3] += bfhi(v.y);
        acc[4] += bflo(v.z); acc[5] += bfhi(v.z);
        acc[6] += bflo(v.w); acc[7] += bfhi(v.w);
    }
    #pragma unroll
    for (int e = 0; e < 8; ++e) sm[r][s * 8 + e] = acc[e] * 0.0625f;
    __syncthreads();

    const int c0 = s, c1 = s + 32;
    float o0 = b2[c0];
    float o1 = (c1 < NC) ? b2[c1] : 0.f;
    for (int k = 0; k < 256; k += 4) {
        f32x4 mv = *(const f32x4*)&sm[r][k];
        #pragma unroll
        for (int e = 0; e < 4; ++e) {
            const float* wrow = W2 + (size_t)(k + e) * NC;
            o0 += mv[e] * wrow[c0];
            if (c1 < NC) o1 += mv[e] * wrow[c1];
        }
    }
    out[(size_t)row * NC + c0] = o0;
    if (c1 < NC) out[(size_t)row * NC + c1] = o1;
}

extern "C" void kernel_launch(void* const* d_in, const int* in_sizes, int n_in,
                              void* d_out, int out_size, void* d_ws, size_t ws_size,
                              hipStream_t stream)
{
    const float* features = (const float*)d_in[0];
    const int*   src0     = (const int*)  d_in[1];
    const int*   src1     = (const int*)  d_in[2];
    const float* W1       = (const float*)d_in[3];
    const float* b1       = (const float*)d_in[4];
    const float* W2       = (const float*)d_in[5];
    const float* b2       = (const float*)d_in[6];
    float*       out      = (float*)d_out;

    unsigned short* Wt    = (unsigned short*)d_ws;        // [NH][K_PAD]  = 128 KB
    unsigned short* H0    = Wt + (size_t)NH * K_PAD;      // [N0][NH] bf16 = 51.2 MB
    unsigned short* h1cat = H0 + (size_t)N0 * NH;         // [N1][256] bf16 = 12.8 MB

    hipLaunchKernelGGL(k0_transpose, dim3(K_PAD / 64), dim3(256), 0, stream, W1, Wt);
    hipLaunchKernelGGL(kA_gemm,   dim3(GRID_A),         dim3(512), 0, stream, features, Wt, H0);
    hipLaunchKernelGGL(kB_gather, dim3((N1 + 15) / 16), dim3(256), 0, stream, H0, src0, b1, h1cat);
    hipLaunchKernelGGL(k2_fused,  dim3(N2 / 8),         dim3(256), 0, stream, h1cat, src1, W2, b2, out);
}